// Round 1
// baseline (3278.285 us; speedup 1.0000x reference)
//
#include <hip/hip_runtime.h>
#include <hip/hip_bf16.h>
#include <math.h>

#define L_LAYERS 4
#define BSZ 64
#define NTOK 196
#define CDIM 768
#define CNDIM 960
#define HIDDIM 3072
#define NHEAD 12
#define HD 64
#define HDK 80
#define MRED 49
#define ROWS (BSZ*NTOK)    /* 12544 */
#define RROWS (BSZ*MRED)   /* 3136 */

typedef __bf16 bf16x8 __attribute__((ext_vector_type(8)));
typedef float f32x4 __attribute__((ext_vector_type(4)));
typedef unsigned short u16x8 __attribute__((ext_vector_type(8)));

static __device__ inline float bf2f(unsigned short u) {
    unsigned int x = ((unsigned int)u) << 16;
    return __builtin_bit_cast(float, x);
}
static __device__ inline unsigned short f2bf(float f) {
    return __builtin_bit_cast(unsigned short, __float2bfloat16(f));
}

// ---------------------------------------------------------------------------
// Weight prep: src fp32 (K x N) row-major -> dst bf16 (N x K) row-major.
// grid.z = layer; per-layer strides passed explicitly (dst layers interleave
// several matrices, so dst layer stride != K*N in general).
// ---------------------------------------------------------------------------
__global__ void transpose_bf16_kernel(const float* __restrict__ src,
                                      unsigned short* __restrict__ dst,
                                      int K, int N, size_t srcLS, size_t dstLS) {
    __shared__ float tile[32][33];
    const float* s = src + (size_t)blockIdx.z * srcLS;
    unsigned short* d = dst + (size_t)blockIdx.z * dstLS;
    int k0 = blockIdx.y * 32, n0 = blockIdx.x * 32;
#pragma unroll
    for (int i = 0; i < 4; i++) {
        int k = k0 + threadIdx.y + i * 8, n = n0 + threadIdx.x;
        if (k < K && n < N) tile[threadIdx.y + i * 8][threadIdx.x] = s[(size_t)k * N + n];
    }
    __syncthreads();
#pragma unroll
    for (int i = 0; i < 4; i++) {
        int n = n0 + threadIdx.y + i * 8, k = k0 + threadIdx.x;
        if (n < N && k < K) d[(size_t)n * K + k] = f2bf(tile[threadIdx.x][threadIdx.y + i * 8]);
    }
}

// ---------------------------------------------------------------------------
// LayerNorm (one wave per row), optional exact GELU, bf16 output.
// ---------------------------------------------------------------------------
__global__ void ln_kernel(const float* __restrict__ x, const float* __restrict__ g,
                          const float* __restrict__ b, unsigned short* __restrict__ y,
                          int M, int C, float eps, int do_gelu) {
    int row = blockIdx.x * 4 + (threadIdx.x >> 6);
    int lane = threadIdx.x & 63;
    if (row >= M) return;
    const float* xr = x + (size_t)row * C;
    float s = 0.f, ss = 0.f;
    for (int c = lane; c < C; c += 64) { float v = xr[c]; s += v; ss += v * v; }
#pragma unroll
    for (int off = 32; off; off >>= 1) { s += __shfl_down(s, off); ss += __shfl_down(ss, off); }
    s = __shfl(s, 0); ss = __shfl(ss, 0);
    float mean = s / (float)C;
    float var = ss / (float)C - mean * mean;
    float rstd = rsqrtf(var + eps);
    unsigned short* yr = y + (size_t)row * C;
    for (int c = lane; c < C; c += 64) {
        float v = (xr[c] - mean) * rstd * g[c] + b[c];
        if (do_gelu) v = 0.5f * v * (1.f + erff(v * 0.70710678118654752f));
        yr[c] = f2bf(v);
    }
}

// ---------------------------------------------------------------------------
// Depthwise 2x2 stride-2 conv on the token grid (14x14 -> 7x7), bf16 in/out.
// r0[b][m][c] = sum_{di,dj} y[b][(2i+di)*14 + 2j+dj][c] * w[c][di*2+dj] + bias[c]
// ---------------------------------------------------------------------------
__global__ void dwconv_kernel(const unsigned short* __restrict__ y,
                              const float* __restrict__ w,
                              const float* __restrict__ bias,
                              unsigned short* __restrict__ r0) {
    int bm = blockIdx.x;
    int b = bm / MRED, m = bm % MRED;
    int i = m / 7, j = m % 7;
    int r00 = b * NTOK + (2 * i) * 14 + 2 * j;
    for (int c = threadIdx.x; c < CDIM; c += 256) {
        float acc = bias[c];
        acc += bf2f(y[(size_t)(r00)      * CDIM + c]) * w[c * 4 + 0];
        acc += bf2f(y[(size_t)(r00 + 1)  * CDIM + c]) * w[c * 4 + 1];
        acc += bf2f(y[(size_t)(r00 + 14) * CDIM + c]) * w[c * 4 + 2];
        acc += bf2f(y[(size_t)(r00 + 15) * CDIM + c]) * w[c * 4 + 3];
        r0[(size_t)bm * CDIM + c] = f2bf(acc);
    }
}

// ---------------------------------------------------------------------------
// MFMA GEMM: C[M,N] = A[M,K] @ Bt[N,K]^T, bf16 inputs, fp32 accumulate.
// MODE 0: out bf16 = acc                    (q, k, v)
// MODE 1: out fp32 = acc + bias             (pw)
// MODE 2: out fp32 += acc + bias            (proj, fc2 residual, in-place)
// MODE 3: out bf16 = gelu(acc + bias)       (fc1)
// Block: 256 threads = 4 waves; tile 128x128, BK=32; wave -> 64x64 quadrant
// as 4x4 grid of 16x16x32 MFMAs.
// ---------------------------------------------------------------------------
template <int MODE>
__global__ __launch_bounds__(256) void gemm_kernel(
    const unsigned short* __restrict__ A,
    const unsigned short* __restrict__ Bt,
    const float* __restrict__ bias,
    float* __restrict__ outF,
    unsigned short* __restrict__ outB,
    int M, int N, int K) {
    __shared__ unsigned short As[128][40];  // +8 pad: 80B row stride, 16B aligned
    __shared__ unsigned short Bs[128][40];
    int m0 = blockIdx.y * 128, n0 = blockIdx.x * 128;
    int tid = threadIdx.x;
    int w = tid >> 6, lane = tid & 63, quad = lane >> 4, l16 = lane & 15;
    int wr = w >> 1, wc = w & 1;

    f32x4 zero4 = {0.f, 0.f, 0.f, 0.f};
    f32x4 acc[4][4];
#pragma unroll
    for (int mi = 0; mi < 4; mi++)
#pragma unroll
        for (int ni = 0; ni < 4; ni++) acc[mi][ni] = zero4;

    u16x8 zero8 = {0, 0, 0, 0, 0, 0, 0, 0};
    int nk = K / 32;
    for (int kb = 0; kb < nk; kb++) {
        int k0 = kb * 32;
#pragma unroll
        for (int t = 0; t < 2; t++) {
            int chunk = tid + t * 256;       // 512 chunks of 8 bf16
            int r = chunk >> 2, c8 = (chunk & 3) * 8;
            int gm = m0 + r;
            u16x8 av = zero8;
            if (gm < M) av = *(const u16x8*)(A + (size_t)gm * K + k0 + c8);
            *(u16x8*)(&As[r][c8]) = av;
            int gn = n0 + r;
            u16x8 bv = zero8;
            if (gn < N) bv = *(const u16x8*)(Bt + (size_t)gn * K + k0 + c8);
            *(u16x8*)(&Bs[r][c8]) = bv;
        }
        __syncthreads();
        bf16x8 af[4], bfr[4];
#pragma unroll
        for (int mi = 0; mi < 4; mi++)
            af[mi] = *(const bf16x8*)(&As[wr * 64 + mi * 16 + l16][quad * 8]);
#pragma unroll
        for (int ni = 0; ni < 4; ni++)
            bfr[ni] = *(const bf16x8*)(&Bs[wc * 64 + ni * 16 + l16][quad * 8]);
#pragma unroll
        for (int mi = 0; mi < 4; mi++)
#pragma unroll
            for (int ni = 0; ni < 4; ni++)
                acc[mi][ni] = __builtin_amdgcn_mfma_f32_16x16x32_bf16(af[mi], bfr[ni], acc[mi][ni], 0, 0, 0);
        __syncthreads();
    }

    // epilogue: D[row = quad*4 + rr][col = l16] within each 16x16 tile
#pragma unroll
    for (int mi = 0; mi < 4; mi++) {
        int rowb = m0 + wr * 64 + mi * 16 + quad * 4;
#pragma unroll
        for (int ni = 0; ni < 4; ni++) {
            int col = n0 + wc * 64 + ni * 16 + l16;
            if (col < N) {
                float bv = 0.f;
                if (MODE != 0) bv = bias[col];
#pragma unroll
                for (int rr = 0; rr < 4; rr++) {
                    int gr = rowb + rr;
                    if (gr < M) {
                        float v = acc[mi][ni][rr] + bv;
                        if (MODE == 3) v = 0.5f * v * (1.f + erff(v * 0.70710678118654752f));
                        if (MODE == 2)      outF[(size_t)gr * N + col] += v;
                        else if (MODE == 1) outF[(size_t)gr * N + col] = v;
                        else                outB[(size_t)gr * N + col] = f2bf(v);
                    }
                }
            }
        }
    }
}

// ---------------------------------------------------------------------------
// Attention: one block per (batch, head). K/V staged in LDS fp32; each thread
// owns one query row (196 rows, 256 threads). M=49 keys -> softmax in regs.
// ---------------------------------------------------------------------------
__global__ __launch_bounds__(256) void attn_kernel(
    const unsigned short* __restrict__ qb,   // (ROWS, CNDIM)
    const unsigned short* __restrict__ kb,   // (RROWS, CNDIM)
    const unsigned short* __restrict__ vb,   // (RROWS, CDIM)
    unsigned short* __restrict__ ob) {       // (ROWS, CDIM)
    __shared__ float ks[MRED][HDK];
    __shared__ float vs[MRED][HD];
    int bh = blockIdx.x;
    int b = bh / NHEAD, h = bh % NHEAD;
    for (int idx = threadIdx.x; idx < MRED * HDK; idx += 256) {
        int m = idx / HDK, d = idx % HDK;
        ks[m][d] = bf2f(kb[(size_t)(b * MRED + m) * CNDIM + h * HDK + d]);
    }
    for (int idx = threadIdx.x; idx < MRED * HD; idx += 256) {
        int m = idx >> 6, d = idx & 63;
        vs[m][d] = bf2f(vb[(size_t)(b * MRED + m) * CDIM + h * HD + d]);
    }
    __syncthreads();
    int n = threadIdx.x;
    if (n >= NTOK) return;
    const unsigned short* qr = qb + (size_t)(b * NTOK + n) * CNDIM + h * HDK;
    float s[MRED];
#pragma unroll
    for (int m = 0; m < MRED; m++) s[m] = 0.f;
    for (int d = 0; d < HDK; d++) {
        float qd = bf2f(qr[d]);
#pragma unroll
        for (int m = 0; m < MRED; m++) s[m] += qd * ks[m][d];
    }
    const float scale = 0.11180339887498949f;  // 1/sqrt(80)
    float mx = -1e30f;
#pragma unroll
    for (int m = 0; m < MRED; m++) { s[m] *= scale; mx = fmaxf(mx, s[m]); }
    float sum = 0.f;
#pragma unroll
    for (int m = 0; m < MRED; m++) { s[m] = __expf(s[m] - mx); sum += s[m]; }
    float inv = 1.f / sum;
#pragma unroll
    for (int m = 0; m < MRED; m++) s[m] *= inv;
    unsigned short* orow = ob + (size_t)(b * NTOK + n) * CDIM + h * HD;
    for (int d = 0; d < HD; d++) {
        float a = 0.f;
#pragma unroll
        for (int m = 0; m < MRED; m++) a += s[m] * vs[m][d];
        orow[d] = f2bf(a);
    }
}

// ---------------------------------------------------------------------------

extern "C" void kernel_launch(void* const* d_in, const int* in_sizes, int n_in,
                              void* d_out, int out_size, void* d_ws, size_t ws_size,
                              hipStream_t stream) {
    (void)in_sizes; (void)n_in; (void)out_size; (void)ws_size;
    const float* x_in   = (const float*)d_in[0];
    const float* q_w    = (const float*)d_in[1];
    const float* dw_w   = (const float*)d_in[2];
    const float* dw_b   = (const float*)d_in[3];
    const float* pw_w   = (const float*)d_in[4];
    const float* pw_b   = (const float*)d_in[5];
    const float* lnr_g  = (const float*)d_in[6];
    const float* lnr_b  = (const float*)d_in[7];
    const float* k_w    = (const float*)d_in[8];
    const float* v_w    = (const float*)d_in[9];
    const float* proj_w = (const float*)d_in[10];
    const float* proj_b = (const float*)d_in[11];
    const float* ln1_g  = (const float*)d_in[12];
    const float* ln1_b  = (const float*)d_in[13];
    const float* ln2_g  = (const float*)d_in[14];
    const float* ln2_b  = (const float*)d_in[15];
    const float* fc1_w  = (const float*)d_in[16];
    const float* fc1_b  = (const float*)d_in[17];
    const float* fc2_w  = (const float*)d_in[18];
    const float* fc2_b  = (const float*)d_in[19];
    float* xout = (float*)d_out;
    char* ws = (char*)d_ws;

    // ---- workspace layout ----
    const size_t PL = 8441856;  // bf16 elements of transposed weights per layer
    const size_t offQ = 0, offPW = 737280, offK = 1474560, offV = 2396160,
                 offPJ = 3133440, offF1 = 3723264, offF2 = 6082560;
    unsigned short* W = (unsigned short*)ws;
    char* act = ws + PL * 2 * L_LAYERS;                 // 67,534,848 B of weights
    unsigned short* y_bf = (unsigned short*)act;        // 12544*768 bf16
    char* blk = act + (size_t)ROWS * CDIM * 2;          // shared attn/mlp block
    unsigned short* q_bf  = (unsigned short*)(blk);                 // 12544*960
    unsigned short* r0_bf = (unsigned short*)(blk + 24084480);      // 3136*768
    float*          pw_f  = (float*)        (blk + 28901376);       // 3136*960 f32
    unsigned short* r_bf  = (unsigned short*)(blk + 40943616);      // 3136*960
    unsigned short* k_bf  = (unsigned short*)(blk + 46964736);      // 3136*960
    unsigned short* v_bf  = (unsigned short*)(blk + 52985856);      // 3136*768
    unsigned short* o_bf  = (unsigned short*)(blk + 57802752);      // 12544*768
    unsigned short* h_bf  = (unsigned short*)(blk);                 // 12544*3072 (aliases q..o, dead by then)
    unsigned short* z_bf  = y_bf;                                   // aliases y (dead)

    // x lives in d_out (fp32) across layers
    hipMemcpyAsync(xout, x_in, (size_t)ROWS * CDIM * sizeof(float),
                   hipMemcpyDeviceToDevice, stream);

    // ---- weight prep (fp32 KxN -> bf16 NxK), all layers via grid.z ----
    dim3 tb(32, 8);
    transpose_bf16_kernel<<<dim3(CNDIM / 32, CDIM / 32, L_LAYERS), tb, 0, stream>>>(
        q_w, W + offQ, CDIM, CNDIM, (size_t)CDIM * CNDIM, PL);
    transpose_bf16_kernel<<<dim3(CNDIM / 32, CDIM / 32, L_LAYERS), tb, 0, stream>>>(
        pw_w, W + offPW, CDIM, CNDIM, (size_t)CDIM * CNDIM, PL);
    transpose_bf16_kernel<<<dim3(CNDIM / 32, CNDIM / 32, L_LAYERS), tb, 0, stream>>>(
        k_w, W + offK, CNDIM, CNDIM, (size_t)CNDIM * CNDIM, PL);
    transpose_bf16_kernel<<<dim3(CDIM / 32, CNDIM / 32, L_LAYERS), tb, 0, stream>>>(
        v_w, W + offV, CNDIM, CDIM, (size_t)CNDIM * CDIM, PL);
    transpose_bf16_kernel<<<dim3(CDIM / 32, CDIM / 32, L_LAYERS), tb, 0, stream>>>(
        proj_w, W + offPJ, CDIM, CDIM, (size_t)CDIM * CDIM, PL);
    transpose_bf16_kernel<<<dim3(HIDDIM / 32, CDIM / 32, L_LAYERS), tb, 0, stream>>>(
        fc1_w, W + offF1, CDIM, HIDDIM, (size_t)CDIM * HIDDIM, PL);
    transpose_bf16_kernel<<<dim3(CDIM / 32, HIDDIM / 32, L_LAYERS), tb, 0, stream>>>(
        fc2_w, W + offF2, HIDDIM, CDIM, (size_t)HIDDIM * CDIM, PL);

    for (int l = 0; l < L_LAYERS; l++) {
        const unsigned short* wl = W + (size_t)l * PL;
        // LN1 -> y
        ln_kernel<<<ROWS / 4, 256, 0, stream>>>(xout, ln1_g + l * CDIM, ln1_b + l * CDIM,
                                                y_bf, ROWS, CDIM, 1e-6f, 0);
        // q = y @ q_w  (12544 x 960 x K=768)
        gemm_kernel<0><<<dim3(8, 98), 256, 0, stream>>>(y_bf, wl + offQ, nullptr, nullptr,
                                                        q_bf, ROWS, CNDIM, CDIM);
        // depthwise conv reduce -> r0 (3136 x 768)
        dwconv_kernel<<<RROWS, 256, 0, stream>>>(y_bf, dw_w + (size_t)l * CDIM * 4,
                                                 dw_b + l * CDIM, r0_bf);
        // pw: r0 @ pw_w + b  (3136 x 960 x 768) -> fp32
        gemm_kernel<1><<<dim3(8, 25), 256, 0, stream>>>(r0_bf, wl + offPW, pw_b + l * CNDIM,
                                                        pw_f, nullptr, RROWS, CNDIM, CDIM);
        // norm_act: LN(eps 1e-5) + exact GELU -> r
        ln_kernel<<<RROWS / 4, 256, 0, stream>>>(pw_f, lnr_g + l * CNDIM, lnr_b + l * CNDIM,
                                                 r_bf, RROWS, CNDIM, 1e-5f, 1);
        // k = r @ k_w (3136 x 960 x 960), v = r @ v_w (3136 x 768 x 960)
        gemm_kernel<0><<<dim3(8, 25), 256, 0, stream>>>(r_bf, wl + offK, nullptr, nullptr,
                                                        k_bf, RROWS, CNDIM, CNDIM);
        gemm_kernel<0><<<dim3(6, 25), 256, 0, stream>>>(r_bf, wl + offV, nullptr, nullptr,
                                                        v_bf, RROWS, CDIM, CNDIM);
        // attention -> o (bf16)
        attn_kernel<<<BSZ * NHEAD, 256, 0, stream>>>(q_bf, k_bf, v_bf, o_bf);
        // x += o @ proj_w + proj_b  (12544 x 768 x 768)
        gemm_kernel<2><<<dim3(6, 98), 256, 0, stream>>>(o_bf, wl + offPJ, proj_b + l * CDIM,
                                                        xout, nullptr, ROWS, CDIM, CDIM);
        // LN2 -> z
        ln_kernel<<<ROWS / 4, 256, 0, stream>>>(xout, ln2_g + l * CDIM, ln2_b + l * CDIM,
                                                z_bf, ROWS, CDIM, 1e-6f, 0);
        // h = gelu(z @ fc1 + b)  (12544 x 3072 x 768) -> bf16
        gemm_kernel<3><<<dim3(24, 98), 256, 0, stream>>>(z_bf, wl + offF1, fc1_b + l * HIDDIM,
                                                         nullptr, h_bf, ROWS, HIDDIM, CDIM);
        // x += h @ fc2 + b  (12544 x 768 x 3072)
        gemm_kernel<2><<<dim3(6, 98), 256, 0, stream>>>(h_bf, wl + offF2, fc2_b + l * CDIM,
                                                        xout, nullptr, ROWS, CDIM, HIDDIM);
    }
}

// Round 2
// 2764.470 us; speedup vs baseline: 1.1859x; 1.1859x over previous
//
#include <hip/hip_runtime.h>
#include <hip/hip_bf16.h>
#include <math.h>

#define L_LAYERS 4
#define BSZ 64
#define NTOK 196
#define CDIM 768
#define CNDIM 960
#define HIDDIM 3072
#define NHEAD 12
#define HD 64
#define HDK 80
#define MRED 49
#define ROWS (BSZ*NTOK)    /* 12544 */
#define RROWS (BSZ*MRED)   /* 3136 */
#define RROWS_PAD 3200     /* 25*128 */

typedef __bf16 bf16x8 __attribute__((ext_vector_type(8)));
typedef float f32x4 __attribute__((ext_vector_type(4)));

static __device__ inline float bf2f(unsigned short u) {
    unsigned int x = ((unsigned int)u) << 16;
    return __builtin_bit_cast(float, x);
}
static __device__ inline unsigned short f2bf(float f) {
    return __builtin_bit_cast(unsigned short, __float2bfloat16(f));
}

// async 16B global -> LDS (wave-uniform LDS base + lane*16)
#define GLLDS16(gsrc, ldst)                                                        \
    __builtin_amdgcn_global_load_lds(                                              \
        (const __attribute__((address_space(1))) unsigned int*)(const void*)(gsrc),\
        (__attribute__((address_space(3))) unsigned int*)(void*)(ldst), 16, 0, 0)

// ---------------------------------------------------------------------------
// Weight prep: src fp32 (K x N) row-major -> dst bf16 (N x K) row-major.
// Padded dst rows (n >= N) are left untouched (poison; harmless, discarded).
// ---------------------------------------------------------------------------
__global__ void transpose_bf16_kernel(const float* __restrict__ src,
                                      unsigned short* __restrict__ dst,
                                      int K, int N, size_t srcLS, size_t dstLS) {
    __shared__ float tile[32][33];
    const float* s = src + (size_t)blockIdx.z * srcLS;
    unsigned short* d = dst + (size_t)blockIdx.z * dstLS;
    int k0 = blockIdx.y * 32, n0 = blockIdx.x * 32;
#pragma unroll
    for (int i = 0; i < 4; i++) {
        int k = k0 + threadIdx.y + i * 8, n = n0 + threadIdx.x;
        if (k < K && n < N) tile[threadIdx.y + i * 8][threadIdx.x] = s[(size_t)k * N + n];
    }
    __syncthreads();
#pragma unroll
    for (int i = 0; i < 4; i++) {
        int n = n0 + threadIdx.y + i * 8, k = k0 + threadIdx.x;
        if (n < N && k < K) d[(size_t)n * K + k] = f2bf(tile[threadIdx.x][threadIdx.y + i * 8]);
    }
}

// ---------------------------------------------------------------------------
// LayerNorm (one wave per row), optional exact GELU, bf16 output.
// ---------------------------------------------------------------------------
__global__ void ln_kernel(const float* __restrict__ x, const float* __restrict__ g,
                          const float* __restrict__ b, unsigned short* __restrict__ y,
                          int M, int C, float eps, int do_gelu) {
    int row = blockIdx.x * 4 + (threadIdx.x >> 6);
    int lane = threadIdx.x & 63;
    if (row >= M) return;
    const float* xr = x + (size_t)row * C;
    float s = 0.f, ss = 0.f;
    for (int c = lane; c < C; c += 64) { float v = xr[c]; s += v; ss += v * v; }
#pragma unroll
    for (int off = 32; off; off >>= 1) { s += __shfl_down(s, off); ss += __shfl_down(ss, off); }
    s = __shfl(s, 0); ss = __shfl(ss, 0);
    float mean = s / (float)C;
    float var = ss / (float)C - mean * mean;
    float rstd = rsqrtf(var + eps);
    unsigned short* yr = y + (size_t)row * C;
    for (int c = lane; c < C; c += 64) {
        float v = (xr[c] - mean) * rstd * g[c] + b[c];
        if (do_gelu) v = 0.5f * v * (1.f + erff(v * 0.70710678118654752f));
        yr[c] = f2bf(v);
    }
}

// ---------------------------------------------------------------------------
// Depthwise 2x2 stride-2 conv on the token grid (14x14 -> 7x7), bf16 in/out.
// ---------------------------------------------------------------------------
__global__ void dwconv_kernel(const unsigned short* __restrict__ y,
                              const float* __restrict__ w,
                              const float* __restrict__ bias,
                              unsigned short* __restrict__ r0) {
    int bm = blockIdx.x;
    int b = bm / MRED, m = bm % MRED;
    int i = m / 7, j = m % 7;
    int r00 = b * NTOK + (2 * i) * 14 + 2 * j;
    for (int c = threadIdx.x; c < CDIM; c += 256) {
        float acc = bias[c];
        acc += bf2f(y[(size_t)(r00)      * CDIM + c]) * w[c * 4 + 0];
        acc += bf2f(y[(size_t)(r00 + 1)  * CDIM + c]) * w[c * 4 + 1];
        acc += bf2f(y[(size_t)(r00 + 14) * CDIM + c]) * w[c * 4 + 2];
        acc += bf2f(y[(size_t)(r00 + 15) * CDIM + c]) * w[c * 4 + 3];
        r0[(size_t)bm * CDIM + c] = f2bf(acc);
    }
}

// ---------------------------------------------------------------------------
// MFMA GEMM (m97 structure): C[M,N] = A[M,K] @ Bt[N,K]^T, bf16 in, fp32 acc.
// global_load_lds width=16 staging, contiguous LDS [128][32], no staging
// guards (buffers padded to 128-multiples of rows). Epilogue guarded.
// MODE 0: out bf16 = acc ; 1: fp32 = acc+bias ; 2: fp32 += acc+bias ;
// MODE 3: bf16 = gelu(acc+bias)
// ---------------------------------------------------------------------------
template <int MODE>
__global__ __launch_bounds__(256) void gemm_kernel(
    const unsigned short* __restrict__ A,
    const unsigned short* __restrict__ Bt,
    const float* __restrict__ bias,
    float* __restrict__ outF,
    unsigned short* __restrict__ outB,
    int M, int N, int K) {
    __shared__ unsigned short As[128 * 32];
    __shared__ unsigned short Bs[128 * 32];
    int m0 = blockIdx.y * 128, n0 = blockIdx.x * 128;
    int tid = threadIdx.x;
    int w = tid >> 6, lane = tid & 63, quad = lane >> 4, l16 = lane & 15;
    int wr = w >> 1, wc = w & 1;

    // staging: chunk ch (16B) -> row ch>>2, short-col (ch&3)*8; LDS offset ch*8
    int r0 = tid >> 2, c0 = (tid & 3) * 8;
    int r1 = (tid + 256) >> 2;               // same c0
    const unsigned short* a0 = A + (size_t)(m0 + r0) * K + c0;
    const unsigned short* a1 = A + (size_t)(m0 + r1) * K + c0;
    const unsigned short* b0 = Bt + (size_t)(n0 + r0) * K + c0;
    const unsigned short* b1 = Bt + (size_t)(n0 + r1) * K + c0;
    unsigned short* lA0 = As + w * 512;          // inst0: chunks w*64 + lane
    unsigned short* lA1 = As + 2048 + w * 512;   // inst1: chunks 256 + w*64 + lane
    unsigned short* lB0 = Bs + w * 512;
    unsigned short* lB1 = Bs + 2048 + w * 512;

    f32x4 zero4 = {0.f, 0.f, 0.f, 0.f};
    f32x4 acc[4][4];
#pragma unroll
    for (int mi = 0; mi < 4; mi++)
#pragma unroll
        for (int ni = 0; ni < 4; ni++) acc[mi][ni] = zero4;

    for (int kb = 0; kb < K; kb += 32) {
        GLLDS16(a0 + kb, lA0);
        GLLDS16(a1 + kb, lA1);
        GLLDS16(b0 + kb, lB0);
        GLLDS16(b1 + kb, lB1);
        __syncthreads();
        bf16x8 af[4], bfr[4];
#pragma unroll
        for (int mi = 0; mi < 4; mi++)
            af[mi] = *(const bf16x8*)(As + (wr * 64 + mi * 16 + l16) * 32 + quad * 8);
#pragma unroll
        for (int ni = 0; ni < 4; ni++)
            bfr[ni] = *(const bf16x8*)(Bs + (wc * 64 + ni * 16 + l16) * 32 + quad * 8);
#pragma unroll
        for (int mi = 0; mi < 4; mi++)
#pragma unroll
            for (int ni = 0; ni < 4; ni++)
                acc[mi][ni] = __builtin_amdgcn_mfma_f32_16x16x32_bf16(af[mi], bfr[ni], acc[mi][ni], 0, 0, 0);
        __syncthreads();
    }

    // epilogue: D[row = quad*4 + rr][col = l16] within each 16x16 tile
#pragma unroll
    for (int mi = 0; mi < 4; mi++) {
        int rowb = m0 + wr * 64 + mi * 16 + quad * 4;
#pragma unroll
        for (int ni = 0; ni < 4; ni++) {
            int col = n0 + wc * 64 + ni * 16 + l16;
            if (col < N) {
                float bv = 0.f;
                if (MODE != 0) bv = bias[col];
#pragma unroll
                for (int rr = 0; rr < 4; rr++) {
                    int gr = rowb + rr;
                    if (gr < M) {
                        float v = acc[mi][ni][rr] + bv;
                        if (MODE == 3) v = 0.5f * v * (1.f + erff(v * 0.70710678118654752f));
                        if (MODE == 2)      outF[(size_t)gr * N + col] += v;
                        else if (MODE == 1) outF[(size_t)gr * N + col] = v;
                        else                outB[(size_t)gr * N + col] = f2bf(v);
                    }
                }
            }
        }
    }
}

// ---------------------------------------------------------------------------
// Attention: one block per (batch, head). K/V staged in LDS fp32; each thread
// owns one query row. M=49 keys -> softmax in regs.
// ---------------------------------------------------------------------------
__global__ __launch_bounds__(256) void attn_kernel(
    const unsigned short* __restrict__ qb,   // (ROWS, CNDIM)
    const unsigned short* __restrict__ kb,   // (RROWS, CNDIM)
    const unsigned short* __restrict__ vb,   // (RROWS, CDIM)
    unsigned short* __restrict__ ob) {       // (ROWS, CDIM)
    __shared__ float ks[MRED][HDK];
    __shared__ float vs[MRED][HD];
    int bh = blockIdx.x;
    int b = bh / NHEAD, h = bh % NHEAD;
    for (int idx = threadIdx.x; idx < MRED * HDK; idx += 256) {
        int m = idx / HDK, d = idx % HDK;
        ks[m][d] = bf2f(kb[(size_t)(b * MRED + m) * CNDIM + h * HDK + d]);
    }
    for (int idx = threadIdx.x; idx < MRED * HD; idx += 256) {
        int m = idx >> 6, d = idx & 63;
        vs[m][d] = bf2f(vb[(size_t)(b * MRED + m) * CDIM + h * HD + d]);
    }
    __syncthreads();
    int n = threadIdx.x;
    if (n >= NTOK) return;
    const unsigned short* qr = qb + (size_t)(b * NTOK + n) * CNDIM + h * HDK;
    float s[MRED];
#pragma unroll
    for (int m = 0; m < MRED; m++) s[m] = 0.f;
    for (int d = 0; d < HDK; d++) {
        float qd = bf2f(qr[d]);
#pragma unroll
        for (int m = 0; m < MRED; m++) s[m] += qd * ks[m][d];
    }
    const float scale = 0.11180339887498949f;  // 1/sqrt(80)
    float mx = -1e30f;
#pragma unroll
    for (int m = 0; m < MRED; m++) { s[m] *= scale; mx = fmaxf(mx, s[m]); }
    float sum = 0.f;
#pragma unroll
    for (int m = 0; m < MRED; m++) { s[m] = __expf(s[m] - mx); sum += s[m]; }
    float inv = 1.f / sum;
#pragma unroll
    for (int m = 0; m < MRED; m++) s[m] *= inv;
    unsigned short* orow = ob + (size_t)(b * NTOK + n) * CDIM + h * HD;
    for (int d = 0; d < HD; d++) {
        float a = 0.f;
#pragma unroll
        for (int m = 0; m < MRED; m++) a += s[m] * vs[m][d];
        orow[d] = f2bf(a);
    }
}

// ---------------------------------------------------------------------------

extern "C" void kernel_launch(void* const* d_in, const int* in_sizes, int n_in,
                              void* d_out, int out_size, void* d_ws, size_t ws_size,
                              hipStream_t stream) {
    (void)in_sizes; (void)n_in; (void)out_size; (void)ws_size;
    const float* x_in   = (const float*)d_in[0];
    const float* q_w    = (const float*)d_in[1];
    const float* dw_w   = (const float*)d_in[2];
    const float* dw_b   = (const float*)d_in[3];
    const float* pw_w   = (const float*)d_in[4];
    const float* pw_b   = (const float*)d_in[5];
    const float* lnr_g  = (const float*)d_in[6];
    const float* lnr_b  = (const float*)d_in[7];
    const float* k_w    = (const float*)d_in[8];
    const float* v_w    = (const float*)d_in[9];
    const float* proj_w = (const float*)d_in[10];
    const float* proj_b = (const float*)d_in[11];
    const float* ln1_g  = (const float*)d_in[12];
    const float* ln1_b  = (const float*)d_in[13];
    const float* ln2_g  = (const float*)d_in[14];
    const float* ln2_b  = (const float*)d_in[15];
    const float* fc1_w  = (const float*)d_in[16];
    const float* fc1_b  = (const float*)d_in[17];
    const float* fc2_w  = (const float*)d_in[18];
    const float* fc2_b  = (const float*)d_in[19];
    float* xout = (float*)d_out;
    char* ws = (char*)d_ws;

    // ---- workspace layout (bf16 elems; weights N-padded to mult of 128) ----
    // q: 1024x768  pw: 1024x768  k: 1024x960  v: 768x960  proj: 768x768
    // fc1: 3072x768  fc2: 768x3072
    const size_t PL = 8601600;
    const size_t offQ = 0, offPW = 786432, offK = 1572864, offV = 2555904,
                 offPJ = 3293184, offF1 = 3883008, offF2 = 6242304;
    unsigned short* W = (unsigned short*)ws;
    char* act = ws + PL * 2 * L_LAYERS;                 // 68,812,800 B weights
    unsigned short* y_bf = (unsigned short*)act;        // 12544*768 bf16
    char* blk = act + (size_t)ROWS * CDIM * 2;
    unsigned short* q_bf  = (unsigned short*)(blk);                 // 12544*960
    unsigned short* r0_bf = (unsigned short*)(blk + 24084480);      // 3200*768 (padded)
    float*          pw_f  = (float*)        (blk + 28999680);       // 3136*960 f32
    unsigned short* r_bf  = (unsigned short*)(blk + 41041920);      // 3200*960 (padded)
    unsigned short* k_bf  = (unsigned short*)(blk + 47185920);      // 3136*960
    unsigned short* v_bf  = (unsigned short*)(blk + 53207040);      // 3136*768
    unsigned short* o_bf  = (unsigned short*)(blk + 58023936);      // 12544*768
    unsigned short* h_bf  = (unsigned short*)(blk);                 // 12544*3072 (aliases, dead by then)
    unsigned short* z_bf  = y_bf;

    hipMemcpyAsync(xout, x_in, (size_t)ROWS * CDIM * sizeof(float),
                   hipMemcpyDeviceToDevice, stream);

    // ---- weight prep (fp32 KxN -> bf16 NxK), all layers via grid.z ----
    dim3 tb(32, 8);
    transpose_bf16_kernel<<<dim3(CNDIM / 32, CDIM / 32, L_LAYERS), tb, 0, stream>>>(
        q_w, W + offQ, CDIM, CNDIM, (size_t)CDIM * CNDIM, PL);
    transpose_bf16_kernel<<<dim3(CNDIM / 32, CDIM / 32, L_LAYERS), tb, 0, stream>>>(
        pw_w, W + offPW, CDIM, CNDIM, (size_t)CDIM * CNDIM, PL);
    transpose_bf16_kernel<<<dim3(CNDIM / 32, CNDIM / 32, L_LAYERS), tb, 0, stream>>>(
        k_w, W + offK, CNDIM, CNDIM, (size_t)CNDIM * CNDIM, PL);
    transpose_bf16_kernel<<<dim3(CDIM / 32, CNDIM / 32, L_LAYERS), tb, 0, stream>>>(
        v_w, W + offV, CNDIM, CDIM, (size_t)CNDIM * CDIM, PL);
    transpose_bf16_kernel<<<dim3(CDIM / 32, CDIM / 32, L_LAYERS), tb, 0, stream>>>(
        proj_w, W + offPJ, CDIM, CDIM, (size_t)CDIM * CDIM, PL);
    transpose_bf16_kernel<<<dim3(HIDDIM / 32, CDIM / 32, L_LAYERS), tb, 0, stream>>>(
        fc1_w, W + offF1, CDIM, HIDDIM, (size_t)CDIM * HIDDIM, PL);
    transpose_bf16_kernel<<<dim3(CDIM / 32, HIDDIM / 32, L_LAYERS), tb, 0, stream>>>(
        fc2_w, W + offF2, HIDDIM, CDIM, (size_t)HIDDIM * CDIM, PL);

    for (int l = 0; l < L_LAYERS; l++) {
        const unsigned short* wl = W + (size_t)l * PL;
        // LN1 -> y
        ln_kernel<<<ROWS / 4, 256, 0, stream>>>(xout, ln1_g + l * CDIM, ln1_b + l * CDIM,
                                                y_bf, ROWS, CDIM, 1e-6f, 0);
        // q = y @ q_w  (12544 x 960 x 768)
        gemm_kernel<0><<<dim3(8, 98), 256, 0, stream>>>(y_bf, wl + offQ, nullptr, nullptr,
                                                        q_bf, ROWS, CNDIM, CDIM);
        // depthwise conv reduce -> r0 (3136 x 768)
        dwconv_kernel<<<RROWS, 256, 0, stream>>>(y_bf, dw_w + (size_t)l * CDIM * 4,
                                                 dw_b + l * CDIM, r0_bf);
        // pw: r0 @ pw_w + b  (3136 x 960 x 768) -> fp32
        gemm_kernel<1><<<dim3(8, 25), 256, 0, stream>>>(r0_bf, wl + offPW, pw_b + l * CNDIM,
                                                        pw_f, nullptr, RROWS, CNDIM, CDIM);
        // norm_act: LN(eps 1e-5) + exact GELU -> r
        ln_kernel<<<RROWS / 4, 256, 0, stream>>>(pw_f, lnr_g + l * CNDIM, lnr_b + l * CNDIM,
                                                 r_bf, RROWS, CNDIM, 1e-5f, 1);
        // k = r @ k_w (3136 x 960 x 960), v = r @ v_w (3136 x 768 x 960)
        gemm_kernel<0><<<dim3(8, 25), 256, 0, stream>>>(r_bf, wl + offK, nullptr, nullptr,
                                                        k_bf, RROWS, CNDIM, CNDIM);
        gemm_kernel<0><<<dim3(6, 25), 256, 0, stream>>>(r_bf, wl + offV, nullptr, nullptr,
                                                        v_bf, RROWS, CDIM, CNDIM);
        // attention -> o (bf16)
        attn_kernel<<<BSZ * NHEAD, 256, 0, stream>>>(q_bf, k_bf, v_bf, o_bf);
        // x += o @ proj_w + proj_b  (12544 x 768 x 768)
        gemm_kernel<2><<<dim3(6, 98), 256, 0, stream>>>(o_bf, wl + offPJ, proj_b + l * CDIM,
                                                        xout, nullptr, ROWS, CDIM, CDIM);
        // LN2 -> z
        ln_kernel<<<ROWS / 4, 256, 0, stream>>>(xout, ln2_g + l * CDIM, ln2_b + l * CDIM,
                                                z_bf, ROWS, CDIM, 1e-6f, 0);
        // h = gelu(z @ fc1 + b)  (12544 x 3072 x 768) -> bf16
        gemm_kernel<3><<<dim3(24, 98), 256, 0, stream>>>(z_bf, wl + offF1, fc1_b + l * HIDDIM,
                                                         nullptr, h_bf, ROWS, HIDDIM, CDIM);
        // x += h @ fc2 + b  (12544 x 768 x 3072)
        gemm_kernel<2><<<dim3(6, 98), 256, 0, stream>>>(h_bf, wl + offF2, fc2_b + l * CDIM,
                                                        xout, nullptr, ROWS, CDIM, HIDDIM);
    }
}

// Round 3
// 2362.366 us; speedup vs baseline: 1.3877x; 1.1702x over previous
//
#include <hip/hip_runtime.h>
#include <hip/hip_bf16.h>
#include <math.h>

#define L_LAYERS 4
#define BSZ 64
#define NTOK 196
#define CDIM 768
#define CNDIM 960
#define HIDDIM 3072
#define NHEAD 12
#define HD 64
#define HDK 80
#define MRED 49
#define ROWS (BSZ*NTOK)    /* 12544 */
#define RROWS (BSZ*MRED)   /* 3136 */
#define RROWS_PAD 3200     /* 25*128 */
#define KVN 1728           /* 960 + 768 fused k|v output cols */

typedef __bf16 bf16x8 __attribute__((ext_vector_type(8)));
typedef float f32x4 __attribute__((ext_vector_type(4)));
typedef unsigned short u16x4 __attribute__((ext_vector_type(4)));

static __device__ inline float bf2f(unsigned short u) {
    unsigned int x = ((unsigned int)u) << 16;
    return __builtin_bit_cast(float, x);
}
static __device__ inline unsigned short f2bf(float f) {
    return __builtin_bit_cast(unsigned short, __float2bfloat16(f));
}
// tanh-form GELU: x*sigmoid(1.5958x + 0.07135x^3); |err vs exact| ~3e-4
static __device__ inline float gelu_f(float x) {
    float t = x * (1.5957691216f + 0.0713548162f * x * x);
    return x * __builtin_amdgcn_rcpf(1.0f + __expf(-t));
}

// async 16B global -> LDS (wave-uniform LDS base + lane*16)
#define GLLDS16(gsrc, ldst)                                                        \
    __builtin_amdgcn_global_load_lds(                                              \
        (const __attribute__((address_space(1))) unsigned int*)(const void*)(gsrc),\
        (__attribute__((address_space(3))) unsigned int*)(void*)(ldst), 16, 0, 0)

// ---------------------------------------------------------------------------
// Weight prep: src fp32 (K x N) row-major -> dst bf16 (N x K) row-major.
// ---------------------------------------------------------------------------
__global__ void transpose_bf16_kernel(const float* __restrict__ src,
                                      unsigned short* __restrict__ dst,
                                      int K, int N, size_t srcLS, size_t dstLS) {
    __shared__ float tile[32][33];
    const float* s = src + (size_t)blockIdx.z * srcLS;
    unsigned short* d = dst + (size_t)blockIdx.z * dstLS;
    int k0 = blockIdx.y * 32, n0 = blockIdx.x * 32;
#pragma unroll
    for (int i = 0; i < 4; i++) {
        int k = k0 + threadIdx.y + i * 8, n = n0 + threadIdx.x;
        if (k < K && n < N) tile[threadIdx.y + i * 8][threadIdx.x] = s[(size_t)k * N + n];
    }
    __syncthreads();
#pragma unroll
    for (int i = 0; i < 4; i++) {
        int n = n0 + threadIdx.y + i * 8, k = k0 + threadIdx.x;
        if (n < N && k < K) d[(size_t)n * K + k] = f2bf(tile[threadIdx.x][threadIdx.y + i * 8]);
    }
}

// ---------------------------------------------------------------------------
// LayerNorm (one wave per row), optional GELU, bf16 output.
// ---------------------------------------------------------------------------
__global__ void ln_kernel(const float* __restrict__ x, const float* __restrict__ g,
                          const float* __restrict__ b, unsigned short* __restrict__ y,
                          int M, int C, float eps, int do_gelu) {
    int row = blockIdx.x * 4 + (threadIdx.x >> 6);
    int lane = threadIdx.x & 63;
    if (row >= M) return;
    const float* xr = x + (size_t)row * C;
    float s = 0.f, ss = 0.f;
    for (int c = lane; c < C; c += 64) { float v = xr[c]; s += v; ss += v * v; }
#pragma unroll
    for (int off = 32; off; off >>= 1) { s += __shfl_down(s, off); ss += __shfl_down(ss, off); }
    s = __shfl(s, 0); ss = __shfl(ss, 0);
    float mean = s / (float)C;
    float var = ss / (float)C - mean * mean;
    float rstd = rsqrtf(var + eps);
    unsigned short* yr = y + (size_t)row * C;
    for (int c = lane; c < C; c += 64) {
        float v = (xr[c] - mean) * rstd * g[c] + b[c];
        if (do_gelu) v = gelu_f(v);
        yr[c] = f2bf(v);
    }
}

// ---------------------------------------------------------------------------
// Depthwise 2x2 stride-2 conv on the token grid (14x14 -> 7x7), bf16 in/out.
// ---------------------------------------------------------------------------
__global__ void dwconv_kernel(const unsigned short* __restrict__ y,
                              const float* __restrict__ w,
                              const float* __restrict__ bias,
                              unsigned short* __restrict__ r0) {
    int bm = blockIdx.x;
    int b = bm / MRED, m = bm % MRED;
    int i = m / 7, j = m % 7;
    int r00 = b * NTOK + (2 * i) * 14 + 2 * j;
    for (int c = threadIdx.x; c < CDIM; c += 256) {
        float acc = bias[c];
        acc += bf2f(y[(size_t)(r00)      * CDIM + c]) * w[c * 4 + 0];
        acc += bf2f(y[(size_t)(r00 + 1)  * CDIM + c]) * w[c * 4 + 1];
        acc += bf2f(y[(size_t)(r00 + 14) * CDIM + c]) * w[c * 4 + 2];
        acc += bf2f(y[(size_t)(r00 + 15) * CDIM + c]) * w[c * 4 + 3];
        r0[(size_t)bm * CDIM + c] = f2bf(acc);
    }
}

// ---------------------------------------------------------------------------
// MFMA GEMM (m97 structure): C[M,N] = A[M,K] @ Bt[N,K]^T, bf16 in, fp32 acc.
// global_load_lds width=16 staging, contiguous LDS, no staging guards
// (buffers row-padded to 128 multiples). Epilogue: LDS-repack -> coalesced
// vector stores. MODE 0: bf16 = acc ; 1: fp32 = acc+bias ;
// 2: fp32 += acc+bias ; 3: bf16 = gelu(acc+bias)
// ---------------------------------------------------------------------------
template <int MODE>
__global__ __launch_bounds__(256) void gemm_kernel(
    const unsigned short* __restrict__ A,
    const unsigned short* __restrict__ Bt,
    const float* __restrict__ bias,
    float* __restrict__ outF,
    unsigned short* __restrict__ outB,
    int M, int N, int K) {
    __shared__ __align__(16) unsigned short smem[8192];   // As 8KB | Bs 8KB
    unsigned short* As = smem;
    unsigned short* Bs = smem + 4096;
    int m0 = blockIdx.y * 128, n0 = blockIdx.x * 128;
    int tid = threadIdx.x;
    int w = tid >> 6, lane = tid & 63, quad = lane >> 4, l16 = lane & 15;
    int wr = w >> 1, wc = w & 1;

    // staging: chunk ch (16B) -> row ch>>2, short-col (ch&3)*8; LDS offset ch*8
    int r0 = tid >> 2, c0 = (tid & 3) * 8;
    int r1 = (tid + 256) >> 2;               // same c0
    const unsigned short* a0 = A + (size_t)(m0 + r0) * K + c0;
    const unsigned short* a1 = A + (size_t)(m0 + r1) * K + c0;
    const unsigned short* b0 = Bt + (size_t)(n0 + r0) * K + c0;
    const unsigned short* b1 = Bt + (size_t)(n0 + r1) * K + c0;
    unsigned short* lA0 = As + w * 512;
    unsigned short* lA1 = As + 2048 + w * 512;
    unsigned short* lB0 = Bs + w * 512;
    unsigned short* lB1 = Bs + 2048 + w * 512;

    f32x4 zero4 = {0.f, 0.f, 0.f, 0.f};
    f32x4 acc[4][4];
#pragma unroll
    for (int mi = 0; mi < 4; mi++)
#pragma unroll
        for (int ni = 0; ni < 4; ni++) acc[mi][ni] = zero4;

    for (int kb = 0; kb < K; kb += 32) {
        GLLDS16(a0 + kb, lA0);
        GLLDS16(a1 + kb, lA1);
        GLLDS16(b0 + kb, lB0);
        GLLDS16(b1 + kb, lB1);
        __syncthreads();
        bf16x8 af[4], bfr[4];
#pragma unroll
        for (int mi = 0; mi < 4; mi++)
            af[mi] = *(const bf16x8*)(As + (wr * 64 + mi * 16 + l16) * 32 + quad * 8);
#pragma unroll
        for (int ni = 0; ni < 4; ni++)
            bfr[ni] = *(const bf16x8*)(Bs + (wc * 64 + ni * 16 + l16) * 32 + quad * 8);
#pragma unroll
        for (int mi = 0; mi < 4; mi++)
#pragma unroll
            for (int ni = 0; ni < 4; ni++)
                acc[mi][ni] = __builtin_amdgcn_mfma_f32_16x16x32_bf16(af[mi], bfr[ni], acc[mi][ni], 0, 0, 0);
        __syncthreads();
    }

    // --- epilogue: repack each wave's 16x64 slice through private 4KB LDS ---
    // (last __syncthreads above guarantees staging LDS is dead)
    float* eld = (float*)smem + w * 1024;
    int colbase = n0 + wc * 64;
#pragma unroll
    for (int mi = 0; mi < 4; mi++) {
#pragma unroll
        for (int ni = 0; ni < 4; ni++)
#pragma unroll
            for (int rr = 0; rr < 4; rr++)
                eld[(quad * 4 + rr) * 64 + ni * 16 + l16] = acc[mi][ni][rr];
        int rowb = m0 + wr * 64 + mi * 16;
        // same-wave DS ops are in-order; compiler inserts lgkmcnt waits
#pragma unroll
        for (int p = 0; p < 4; p++) {
            int r = p * 4 + quad;
            int c = l16 * 4;
            int gr = rowb + r, gc = colbase + c;
            if (gc < N && gr < M) {
                f32x4 v4 = *(f32x4*)(eld + r * 64 + c);
                if (MODE == 0) {
                    u16x4 h;
#pragma unroll
                    for (int e = 0; e < 4; e++) h[e] = f2bf(v4[e]);
                    *(u16x4*)(outB + (size_t)gr * N + gc) = h;
                } else {
                    f32x4 b4 = *(const f32x4*)(bias + gc);
                    if (MODE == 1) {
                        *(f32x4*)(outF + (size_t)gr * N + gc) = v4 + b4;
                    } else if (MODE == 2) {
                        f32x4 o4 = *(f32x4*)(outF + (size_t)gr * N + gc);
                        *(f32x4*)(outF + (size_t)gr * N + gc) = o4 + v4 + b4;
                    } else {  // MODE 3
                        u16x4 h;
#pragma unroll
                        for (int e = 0; e < 4; e++) h[e] = f2bf(gelu_f(v4[e] + b4[e]));
                        *(u16x4*)(outB + (size_t)gr * N + gc) = h;
                    }
                }
            }
        }
    }
}

// ---------------------------------------------------------------------------
// Attention: one block per (batch, head). K/V staged in LDS fp32; each thread
// owns one query row. kv is the fused (RROWS x KVN) buffer: k cols 0..959,
// v cols 960..1727.
// ---------------------------------------------------------------------------
__global__ __launch_bounds__(256) void attn_kernel(
    const unsigned short* __restrict__ qb,   // (ROWS, CNDIM)
    const unsigned short* __restrict__ kv,   // (RROWS, KVN)
    unsigned short* __restrict__ ob) {       // (ROWS, CDIM)
    __shared__ float ks[MRED][HDK];
    __shared__ float vs[MRED][HD];
    int bh = blockIdx.x;
    int b = bh / NHEAD, h = bh % NHEAD;
    for (int idx = threadIdx.x; idx < MRED * HDK; idx += 256) {
        int m = idx / HDK, d = idx % HDK;
        ks[m][d] = bf2f(kv[(size_t)(b * MRED + m) * KVN + h * HDK + d]);
    }
    for (int idx = threadIdx.x; idx < MRED * HD; idx += 256) {
        int m = idx >> 6, d = idx & 63;
        vs[m][d] = bf2f(kv[(size_t)(b * MRED + m) * KVN + 960 + h * HD + d]);
    }
    __syncthreads();
    int n = threadIdx.x;
    if (n >= NTOK) return;
    const unsigned short* qr = qb + (size_t)(b * NTOK + n) * CNDIM + h * HDK;
    float s[MRED];
#pragma unroll
    for (int m = 0; m < MRED; m++) s[m] = 0.f;
    for (int d = 0; d < HDK; d++) {
        float qd = bf2f(qr[d]);
#pragma unroll
        for (int m = 0; m < MRED; m++) s[m] += qd * ks[m][d];
    }
    const float scale = 0.11180339887498949f;  // 1/sqrt(80)
    float mx = -1e30f;
#pragma unroll
    for (int m = 0; m < MRED; m++) { s[m] *= scale; mx = fmaxf(mx, s[m]); }
    float sum = 0.f;
#pragma unroll
    for (int m = 0; m < MRED; m++) { s[m] = __expf(s[m] - mx); sum += s[m]; }
    float inv = 1.f / sum;
#pragma unroll
    for (int m = 0; m < MRED; m++) s[m] *= inv;
    unsigned short* orow = ob + (size_t)(b * NTOK + n) * CDIM + h * HD;
    for (int d = 0; d < HD; d++) {
        float a = 0.f;
#pragma unroll
        for (int m = 0; m < MRED; m++) a += s[m] * vs[m][d];
        orow[d] = f2bf(a);
    }
}

// ---------------------------------------------------------------------------

extern "C" void kernel_launch(void* const* d_in, const int* in_sizes, int n_in,
                              void* d_out, int out_size, void* d_ws, size_t ws_size,
                              hipStream_t stream) {
    (void)in_sizes; (void)n_in; (void)out_size; (void)ws_size;
    const float* x_in   = (const float*)d_in[0];
    const float* q_w    = (const float*)d_in[1];
    const float* dw_w   = (const float*)d_in[2];
    const float* dw_b   = (const float*)d_in[3];
    const float* pw_w   = (const float*)d_in[4];
    const float* pw_b   = (const float*)d_in[5];
    const float* lnr_g  = (const float*)d_in[6];
    const float* lnr_b  = (const float*)d_in[7];
    const float* k_w    = (const float*)d_in[8];
    const float* v_w    = (const float*)d_in[9];
    const float* proj_w = (const float*)d_in[10];
    const float* proj_b = (const float*)d_in[11];
    const float* ln1_g  = (const float*)d_in[12];
    const float* ln1_b  = (const float*)d_in[13];
    const float* ln2_g  = (const float*)d_in[14];
    const float* ln2_b  = (const float*)d_in[15];
    const float* fc1_w  = (const float*)d_in[16];
    const float* fc1_b  = (const float*)d_in[17];
    const float* fc2_w  = (const float*)d_in[18];
    const float* fc2_b  = (const float*)d_in[19];
    float* xout = (float*)d_out;
    char* ws = (char*)d_ws;

    // ---- workspace layout (bf16 elems; weight rows padded to mult of 128) ----
    // q: 1024x768  pw: 1024x768  kv: 1792x960 (k rows 0..959, v rows 960..1727)
    // proj: 768x768  fc1: 3072x768  fc2: 768x3072
    const size_t PL = 8601600;
    const size_t offQ = 0, offPW = 786432, offKV = 1572864,
                 offPJ = 3293184, offF1 = 3883008, offF2 = 6242304;
    unsigned short* W = (unsigned short*)ws;
    char* act = ws + PL * 2 * L_LAYERS;                 // 68,812,800 B weights
    unsigned short* y_bf = (unsigned short*)act;        // 12544*768 bf16
    char* blk = act + (size_t)ROWS * CDIM * 2;
    unsigned short* q_bf  = (unsigned short*)(blk);                 // 12544*960
    unsigned short* r0_bf = (unsigned short*)(blk + 24084480);      // 3200*768 (padded)
    float*          pw_f  = (float*)        (blk + 28999680);       // 3136*960 f32
    unsigned short* r_bf  = (unsigned short*)(blk + 41041920);      // 3200*960 (padded)
    unsigned short* kv_bf = (unsigned short*)(blk + 47185920);      // 3136*1728
    unsigned short* o_bf  = (unsigned short*)(blk + 58023936);      // 12544*768
    unsigned short* h_bf  = (unsigned short*)(blk);                 // 12544*3072 (aliases, dead by then)
    unsigned short* z_bf  = y_bf;

    hipMemcpyAsync(xout, x_in, (size_t)ROWS * CDIM * sizeof(float),
                   hipMemcpyDeviceToDevice, stream);

    // ---- weight prep (fp32 KxN -> bf16 NxK), all layers via grid.z ----
    dim3 tb(32, 8);
    transpose_bf16_kernel<<<dim3(CNDIM / 32, CDIM / 32, L_LAYERS), tb, 0, stream>>>(
        q_w, W + offQ, CDIM, CNDIM, (size_t)CDIM * CNDIM, PL);
    transpose_bf16_kernel<<<dim3(CNDIM / 32, CDIM / 32, L_LAYERS), tb, 0, stream>>>(
        pw_w, W + offPW, CDIM, CNDIM, (size_t)CDIM * CNDIM, PL);
    transpose_bf16_kernel<<<dim3(CNDIM / 32, CNDIM / 32, L_LAYERS), tb, 0, stream>>>(
        k_w, W + offKV, CNDIM, CNDIM, (size_t)CNDIM * CNDIM, PL);
    transpose_bf16_kernel<<<dim3(CDIM / 32, CNDIM / 32, L_LAYERS), tb, 0, stream>>>(
        v_w, W + offKV + (size_t)CNDIM * CNDIM, CNDIM, CDIM, (size_t)CNDIM * CDIM, PL);
    transpose_bf16_kernel<<<dim3(CDIM / 32, CDIM / 32, L_LAYERS), tb, 0, stream>>>(
        proj_w, W + offPJ, CDIM, CDIM, (size_t)CDIM * CDIM, PL);
    transpose_bf16_kernel<<<dim3(HIDDIM / 32, CDIM / 32, L_LAYERS), tb, 0, stream>>>(
        fc1_w, W + offF1, CDIM, HIDDIM, (size_t)CDIM * HIDDIM, PL);
    transpose_bf16_kernel<<<dim3(CDIM / 32, HIDDIM / 32, L_LAYERS), tb, 0, stream>>>(
        fc2_w, W + offF2, HIDDIM, CDIM, (size_t)HIDDIM * CDIM, PL);

    for (int l = 0; l < L_LAYERS; l++) {
        const unsigned short* wl = W + (size_t)l * PL;
        // LN1 -> y
        ln_kernel<<<ROWS / 4, 256, 0, stream>>>(xout, ln1_g + l * CDIM, ln1_b + l * CDIM,
                                                y_bf, ROWS, CDIM, 1e-6f, 0);
        // q = y @ q_w  (12544 x 960 x 768)
        gemm_kernel<0><<<dim3(8, 98), 256, 0, stream>>>(y_bf, wl + offQ, nullptr, nullptr,
                                                        q_bf, ROWS, CNDIM, CDIM);
        // depthwise conv reduce -> r0 (3136 x 768)
        dwconv_kernel<<<RROWS, 256, 0, stream>>>(y_bf, dw_w + (size_t)l * CDIM * 4,
                                                 dw_b + l * CDIM, r0_bf);
        // pw: r0 @ pw_w + b  (3136 x 960 x 768) -> fp32
        gemm_kernel<1><<<dim3(8, 25), 256, 0, stream>>>(r0_bf, wl + offPW, pw_b + l * CNDIM,
                                                        pw_f, nullptr, RROWS, CNDIM, CDIM);
        // norm_act: LN(eps 1e-5) + GELU -> r
        ln_kernel<<<RROWS / 4, 256, 0, stream>>>(pw_f, lnr_g + l * CNDIM, lnr_b + l * CNDIM,
                                                 r_bf, RROWS, CNDIM, 1e-5f, 1);
        // fused kv = r @ [k_w | v_w]  (3136 x 1728 x 960)
        gemm_kernel<0><<<dim3(14, 25), 256, 0, stream>>>(r_bf, wl + offKV, nullptr, nullptr,
                                                         kv_bf, RROWS, KVN, CNDIM);
        // attention -> o (bf16)
        attn_kernel<<<BSZ * NHEAD, 256, 0, stream>>>(q_bf, kv_bf, o_bf);
        // x += o @ proj_w + proj_b  (12544 x 768 x 768)
        gemm_kernel<2><<<dim3(6, 98), 256, 0, stream>>>(o_bf, wl + offPJ, proj_b + l * CDIM,
                                                        xout, nullptr, ROWS, CDIM, CDIM);
        // LN2 -> z
        ln_kernel<<<ROWS / 4, 256, 0, stream>>>(xout, ln2_g + l * CDIM, ln2_b + l * CDIM,
                                                z_bf, ROWS, CDIM, 1e-6f, 0);
        // h = gelu(z @ fc1 + b)  (12544 x 3072 x 768) -> bf16
        gemm_kernel<3><<<dim3(24, 98), 256, 0, stream>>>(z_bf, wl + offF1, fc1_b + l * HIDDIM,
                                                         nullptr, h_bf, ROWS, HIDDIM, CDIM);
        // x += h @ fc2 + b  (12544 x 768 x 3072)
        gemm_kernel<2><<<dim3(6, 98), 256, 0, stream>>>(h_bf, wl + offF2, fc2_b + l * CDIM,
                                                        xout, nullptr, ROWS, CDIM, HIDDIM);
    }
}

// Round 4
// 2253.103 us; speedup vs baseline: 1.4550x; 1.0485x over previous
//
#include <hip/hip_runtime.h>
#include <hip/hip_bf16.h>
#include <math.h>

#define L_LAYERS 4
#define BSZ 64
#define NTOK 196
#define CDIM 768
#define CNDIM 960
#define HIDDIM 3072
#define NHEAD 12
#define HD 64
#define HDK 80
#define MRED 49
#define ROWS (BSZ*NTOK)    /* 12544 */
#define RROWS (BSZ*MRED)   /* 3136 */
#define RROWS_PAD 3200     /* 25*128 */
#define KVN 1728           /* 960 + 768 fused k|v output cols */

typedef __bf16 bf16x8 __attribute__((ext_vector_type(8)));
typedef float f32x4 __attribute__((ext_vector_type(4)));
typedef unsigned short u16x4 __attribute__((ext_vector_type(4)));

static __device__ inline float bf2f(unsigned short u) {
    unsigned int x = ((unsigned int)u) << 16;
    return __builtin_bit_cast(float, x);
}
static __device__ inline unsigned short f2bf(float f) {
    return __builtin_bit_cast(unsigned short, __float2bfloat16(f));
}
// tanh-form GELU: x*sigmoid(1.5958x + 0.07135x^3); |err vs exact| ~3e-4
static __device__ inline float gelu_f(float x) {
    float t = x * (1.5957691216f + 0.0713548162f * x * x);
    return x * __builtin_amdgcn_rcpf(1.0f + __expf(-t));
}

// async 16B global -> LDS (wave-uniform LDS base + lane*16)
#define GLLDS16(gsrc, ldst)                                                        \
    __builtin_amdgcn_global_load_lds(                                              \
        (const __attribute__((address_space(1))) unsigned int*)(const void*)(gsrc),\
        (__attribute__((address_space(3))) unsigned int*)(void*)(ldst), 16, 0, 0)

// ---------------------------------------------------------------------------
// Weight prep: src fp32 (K x N) row-major -> dst bf16 (N x K) row-major.
// ---------------------------------------------------------------------------
__global__ void transpose_bf16_kernel(const float* __restrict__ src,
                                      unsigned short* __restrict__ dst,
                                      int K, int N, size_t srcLS, size_t dstLS) {
    __shared__ float tile[32][33];
    const float* s = src + (size_t)blockIdx.z * srcLS;
    unsigned short* d = dst + (size_t)blockIdx.z * dstLS;
    int k0 = blockIdx.y * 32, n0 = blockIdx.x * 32;
#pragma unroll
    for (int i = 0; i < 4; i++) {
        int k = k0 + threadIdx.y + i * 8, n = n0 + threadIdx.x;
        if (k < K && n < N) tile[threadIdx.y + i * 8][threadIdx.x] = s[(size_t)k * N + n];
    }
    __syncthreads();
#pragma unroll
    for (int i = 0; i < 4; i++) {
        int n = n0 + threadIdx.y + i * 8, k = k0 + threadIdx.x;
        if (n < N && k < K) d[(size_t)n * K + k] = f2bf(tile[threadIdx.x][threadIdx.y + i * 8]);
    }
}

// ---------------------------------------------------------------------------
// LayerNorm (one wave per row), optional GELU, bf16 output.
// ---------------------------------------------------------------------------
__global__ void ln_kernel(const float* __restrict__ x, const float* __restrict__ g,
                          const float* __restrict__ b, unsigned short* __restrict__ y,
                          int M, int C, float eps, int do_gelu) {
    int row = blockIdx.x * 4 + (threadIdx.x >> 6);
    int lane = threadIdx.x & 63;
    if (row >= M) return;
    const float* xr = x + (size_t)row * C;
    float s = 0.f, ss = 0.f;
    for (int c = lane; c < C; c += 64) { float v = xr[c]; s += v; ss += v * v; }
#pragma unroll
    for (int off = 32; off; off >>= 1) { s += __shfl_down(s, off); ss += __shfl_down(ss, off); }
    s = __shfl(s, 0); ss = __shfl(ss, 0);
    float mean = s / (float)C;
    float var = ss / (float)C - mean * mean;
    float rstd = rsqrtf(var + eps);
    unsigned short* yr = y + (size_t)row * C;
    for (int c = lane; c < C; c += 64) {
        float v = (xr[c] - mean) * rstd * g[c] + b[c];
        if (do_gelu) v = gelu_f(v);
        yr[c] = f2bf(v);
    }
}

// ---------------------------------------------------------------------------
// Depthwise 2x2 stride-2 conv on the token grid (14x14 -> 7x7), bf16 in/out.
// ---------------------------------------------------------------------------
__global__ void dwconv_kernel(const unsigned short* __restrict__ y,
                              const float* __restrict__ w,
                              const float* __restrict__ bias,
                              unsigned short* __restrict__ r0) {
    int bm = blockIdx.x;
    int b = bm / MRED, m = bm % MRED;
    int i = m / 7, j = m % 7;
    int r00 = b * NTOK + (2 * i) * 14 + 2 * j;
    for (int c = threadIdx.x; c < CDIM; c += 256) {
        float acc = bias[c];
        acc += bf2f(y[(size_t)(r00)      * CDIM + c]) * w[c * 4 + 0];
        acc += bf2f(y[(size_t)(r00 + 1)  * CDIM + c]) * w[c * 4 + 1];
        acc += bf2f(y[(size_t)(r00 + 14) * CDIM + c]) * w[c * 4 + 2];
        acc += bf2f(y[(size_t)(r00 + 15) * CDIM + c]) * w[c * 4 + 3];
        r0[(size_t)bm * CDIM + c] = f2bf(acc);
    }
}

// ---------------------------------------------------------------------------
// MFMA GEMM (m97 structure): C[M,N] = A[M,K] @ Bt[N,K]^T, bf16 in, fp32 acc.
// 1D grid with XCD-aware tile swizzle: groups of 8 row-tiles x NC col-tiles;
// within a group local = col*8 + row%8, so all col-blocks of one A-row-tile
// share id%8 -> same XCD -> A-tile fetched from HBM once per row.
// MODE 0: bf16 = acc ; 1: fp32 = acc+bias ; 2: fp32 += acc+bias ;
// 3: bf16 = gelu(acc+bias)
// ---------------------------------------------------------------------------
template <int MODE>
__global__ __launch_bounds__(256) void gemm_kernel(
    const unsigned short* __restrict__ A,
    const unsigned short* __restrict__ Bt,
    const float* __restrict__ bias,
    float* __restrict__ outF,
    unsigned short* __restrict__ outB,
    int M, int N, int K, int NR, int NC) {
    __shared__ __align__(16) unsigned short smem[8192];   // As 8KB | Bs 8KB
    unsigned short* As = smem;
    unsigned short* Bs = smem + 4096;

    // tile swizzle
    int id = blockIdx.x;
    int gsize = 8 * NC;
    int g = id / gsize;
    int local = id - g * gsize;
    int rbase = g * 8;
    int Gg = NR - rbase; if (Gg > 8) Gg = 8;
    int col = local / Gg;
    int row = rbase + (local - col * Gg);
    int m0 = row * 128, n0 = col * 128;

    int tid = threadIdx.x;
    int w = tid >> 6, lane = tid & 63, quad = lane >> 4, l16 = lane & 15;
    int wr = w >> 1, wc = w & 1;

    // staging: chunk ch (16B) -> row ch>>2, short-col (ch&3)*8; LDS offset ch*8
    int r0 = tid >> 2, c0 = (tid & 3) * 8;
    int r1 = (tid + 256) >> 2;               // same c0
    const unsigned short* a0 = A + (size_t)(m0 + r0) * K + c0;
    const unsigned short* a1 = A + (size_t)(m0 + r1) * K + c0;
    const unsigned short* b0 = Bt + (size_t)(n0 + r0) * K + c0;
    const unsigned short* b1 = Bt + (size_t)(n0 + r1) * K + c0;
    unsigned short* lA0 = As + w * 512;
    unsigned short* lA1 = As + 2048 + w * 512;
    unsigned short* lB0 = Bs + w * 512;
    unsigned short* lB1 = Bs + 2048 + w * 512;

    f32x4 zero4 = {0.f, 0.f, 0.f, 0.f};
    f32x4 acc[4][4];
#pragma unroll
    for (int mi = 0; mi < 4; mi++)
#pragma unroll
        for (int ni = 0; ni < 4; ni++) acc[mi][ni] = zero4;

    for (int kb = 0; kb < K; kb += 32) {
        GLLDS16(a0 + kb, lA0);
        GLLDS16(a1 + kb, lA1);
        GLLDS16(b0 + kb, lB0);
        GLLDS16(b1 + kb, lB1);
        __syncthreads();
        bf16x8 af[4], bfr[4];
#pragma unroll
        for (int mi = 0; mi < 4; mi++)
            af[mi] = *(const bf16x8*)(As + (wr * 64 + mi * 16 + l16) * 32 + quad * 8);
#pragma unroll
        for (int ni = 0; ni < 4; ni++)
            bfr[ni] = *(const bf16x8*)(Bs + (wc * 64 + ni * 16 + l16) * 32 + quad * 8);
#pragma unroll
        for (int mi = 0; mi < 4; mi++)
#pragma unroll
            for (int ni = 0; ni < 4; ni++)
                acc[mi][ni] = __builtin_amdgcn_mfma_f32_16x16x32_bf16(af[mi], bfr[ni], acc[mi][ni], 0, 0, 0);
        __syncthreads();
    }

    // --- epilogue: repack each wave's 16x64 slice through private 4KB LDS ---
    float* eld = (float*)smem + w * 1024;
    int colbase = n0 + wc * 64;
#pragma unroll
    for (int mi = 0; mi < 4; mi++) {
#pragma unroll
        for (int ni = 0; ni < 4; ni++)
#pragma unroll
            for (int rr = 0; rr < 4; rr++)
                eld[(quad * 4 + rr) * 64 + ni * 16 + l16] = acc[mi][ni][rr];
        int rowb = m0 + wr * 64 + mi * 16;
#pragma unroll
        for (int p = 0; p < 4; p++) {
            int r = p * 4 + quad;
            int c = l16 * 4;
            int gr = rowb + r, gc = colbase + c;
            if (gc < N && gr < M) {
                f32x4 v4 = *(f32x4*)(eld + r * 64 + c);
                if (MODE == 0) {
                    u16x4 h;
#pragma unroll
                    for (int e = 0; e < 4; e++) h[e] = f2bf(v4[e]);
                    *(u16x4*)(outB + (size_t)gr * N + gc) = h;
                } else {
                    f32x4 b4 = *(const f32x4*)(bias + gc);
                    if (MODE == 1) {
                        *(f32x4*)(outF + (size_t)gr * N + gc) = v4 + b4;
                    } else if (MODE == 2) {
                        f32x4 o4 = *(f32x4*)(outF + (size_t)gr * N + gc);
                        *(f32x4*)(outF + (size_t)gr * N + gc) = o4 + v4 + b4;
                    } else {  // MODE 3
                        u16x4 h;
#pragma unroll
                        for (int e = 0; e < 4; e++) h[e] = f2bf(gelu_f(v4[e] + b4[e]));
                        *(u16x4*)(outB + (size_t)gr * N + gc) = h;
                    }
                }
            }
        }
    }
}

// ---------------------------------------------------------------------------
// Attention: one block per (batch, head). K/V staged in LDS fp32; each thread
// owns one query row. kv fused (RROWS x KVN): k cols 0..959, v cols 960..1727.
// ---------------------------------------------------------------------------
__global__ __launch_bounds__(256) void attn_kernel(
    const unsigned short* __restrict__ qb,   // (ROWS, CNDIM)
    const unsigned short* __restrict__ kv,   // (RROWS, KVN)
    unsigned short* __restrict__ ob) {       // (ROWS, CDIM)
    __shared__ float ks[MRED][HDK];
    __shared__ float vs[MRED][HD];
    int bh = blockIdx.x;
    int b = bh / NHEAD, h = bh % NHEAD;
    for (int idx = threadIdx.x; idx < MRED * HDK; idx += 256) {
        int m = idx / HDK, d = idx % HDK;
        ks[m][d] = bf2f(kv[(size_t)(b * MRED + m) * KVN + h * HDK + d]);
    }
    for (int idx = threadIdx.x; idx < MRED * HD; idx += 256) {
        int m = idx >> 6, d = idx & 63;
        vs[m][d] = bf2f(kv[(size_t)(b * MRED + m) * KVN + 960 + h * HD + d]);
    }
    __syncthreads();
    int n = threadIdx.x;
    if (n >= NTOK) return;
    const unsigned short* qr = qb + (size_t)(b * NTOK + n) * CNDIM + h * HDK;
    float s[MRED];
#pragma unroll
    for (int m = 0; m < MRED; m++) s[m] = 0.f;
    for (int d = 0; d < HDK; d++) {
        float qd = bf2f(qr[d]);
#pragma unroll
        for (int m = 0; m < MRED; m++) s[m] += qd * ks[m][d];
    }
    const float scale = 0.11180339887498949f;  // 1/sqrt(80)
    float mx = -1e30f;
#pragma unroll
    for (int m = 0; m < MRED; m++) { s[m] *= scale; mx = fmaxf(mx, s[m]); }
    float sum = 0.f;
#pragma unroll
    for (int m = 0; m < MRED; m++) { s[m] = __expf(s[m] - mx); sum += s[m]; }
    float inv = 1.f / sum;
#pragma unroll
    for (int m = 0; m < MRED; m++) s[m] *= inv;
    unsigned short* orow = ob + (size_t)(b * NTOK + n) * CDIM + h * HD;
    for (int d = 0; d < HD; d++) {
        float a = 0.f;
#pragma unroll
        for (int m = 0; m < MRED; m++) a += s[m] * vs[m][d];
        orow[d] = f2bf(a);
    }
}

// ---------------------------------------------------------------------------

extern "C" void kernel_launch(void* const* d_in, const int* in_sizes, int n_in,
                              void* d_out, int out_size, void* d_ws, size_t ws_size,
                              hipStream_t stream) {
    (void)in_sizes; (void)n_in; (void)out_size; (void)ws_size;
    const float* x_in   = (const float*)d_in[0];
    const float* q_w    = (const float*)d_in[1];
    const float* dw_w   = (const float*)d_in[2];
    const float* dw_b   = (const float*)d_in[3];
    const float* pw_w   = (const float*)d_in[4];
    const float* pw_b   = (const float*)d_in[5];
    const float* lnr_g  = (const float*)d_in[6];
    const float* lnr_b  = (const float*)d_in[7];
    const float* k_w    = (const float*)d_in[8];
    const float* v_w    = (const float*)d_in[9];
    const float* proj_w = (const float*)d_in[10];
    const float* proj_b = (const float*)d_in[11];
    const float* ln1_g  = (const float*)d_in[12];
    const float* ln1_b  = (const float*)d_in[13];
    const float* ln2_g  = (const float*)d_in[14];
    const float* ln2_b  = (const float*)d_in[15];
    const float* fc1_w  = (const float*)d_in[16];
    const float* fc1_b  = (const float*)d_in[17];
    const float* fc2_w  = (const float*)d_in[18];
    const float* fc2_b  = (const float*)d_in[19];
    float* xout = (float*)d_out;
    char* ws = (char*)d_ws;

    // ---- workspace layout (bf16 elems; weight rows padded to mult of 128) ----
    const size_t PL = 8601600;
    const size_t offQ = 0, offPW = 786432, offKV = 1572864,
                 offPJ = 3293184, offF1 = 3883008, offF2 = 6242304;
    unsigned short* W = (unsigned short*)ws;
    char* act = ws + PL * 2 * L_LAYERS;                 // 68,812,800 B weights
    unsigned short* y_bf = (unsigned short*)act;        // 12544*768 bf16
    char* blk = act + (size_t)ROWS * CDIM * 2;
    unsigned short* q_bf  = (unsigned short*)(blk);                 // 12544*960
    unsigned short* r0_bf = (unsigned short*)(blk + 24084480);      // 3200*768 (padded)
    float*          pw_f  = (float*)        (blk + 28999680);       // 3136*960 f32
    unsigned short* r_bf  = (unsigned short*)(blk + 41041920);      // 3200*960 (padded)
    unsigned short* kv_bf = (unsigned short*)(blk + 47185920);      // 3136*1728
    unsigned short* o_bf  = (unsigned short*)(blk + 58023936);      // 12544*768
    unsigned short* h_bf  = (unsigned short*)(blk);                 // 12544*3072 (aliases, dead by then)
    unsigned short* z_bf  = y_bf;

    hipMemcpyAsync(xout, x_in, (size_t)ROWS * CDIM * sizeof(float),
                   hipMemcpyDeviceToDevice, stream);

    // ---- weight prep (fp32 KxN -> bf16 NxK), all layers via grid.z ----
    dim3 tb(32, 8);
    transpose_bf16_kernel<<<dim3(CNDIM / 32, CDIM / 32, L_LAYERS), tb, 0, stream>>>(
        q_w, W + offQ, CDIM, CNDIM, (size_t)CDIM * CNDIM, PL);
    transpose_bf16_kernel<<<dim3(CNDIM / 32, CDIM / 32, L_LAYERS), tb, 0, stream>>>(
        pw_w, W + offPW, CDIM, CNDIM, (size_t)CDIM * CNDIM, PL);
    transpose_bf16_kernel<<<dim3(CNDIM / 32, CNDIM / 32, L_LAYERS), tb, 0, stream>>>(
        k_w, W + offKV, CNDIM, CNDIM, (size_t)CNDIM * CNDIM, PL);
    transpose_bf16_kernel<<<dim3(CDIM / 32, CNDIM / 32, L_LAYERS), tb, 0, stream>>>(
        v_w, W + offKV + (size_t)CNDIM * CNDIM, CNDIM, CDIM, (size_t)CNDIM * CDIM, PL);
    transpose_bf16_kernel<<<dim3(CDIM / 32, CDIM / 32, L_LAYERS), tb, 0, stream>>>(
        proj_w, W + offPJ, CDIM, CDIM, (size_t)CDIM * CDIM, PL);
    transpose_bf16_kernel<<<dim3(HIDDIM / 32, CDIM / 32, L_LAYERS), tb, 0, stream>>>(
        fc1_w, W + offF1, CDIM, HIDDIM, (size_t)CDIM * HIDDIM, PL);
    transpose_bf16_kernel<<<dim3(CDIM / 32, HIDDIM / 32, L_LAYERS), tb, 0, stream>>>(
        fc2_w, W + offF2, HIDDIM, CDIM, (size_t)HIDDIM * CDIM, PL);

    for (int l = 0; l < L_LAYERS; l++) {
        const unsigned short* wl = W + (size_t)l * PL;
        // LN1 -> y
        ln_kernel<<<ROWS / 4, 256, 0, stream>>>(xout, ln1_g + l * CDIM, ln1_b + l * CDIM,
                                                y_bf, ROWS, CDIM, 1e-6f, 0);
        // q = y @ q_w  (12544 x 960 x 768), NR=98 NC=8
        gemm_kernel<0><<<98 * 8, 256, 0, stream>>>(y_bf, wl + offQ, nullptr, nullptr,
                                                   q_bf, ROWS, CNDIM, CDIM, 98, 8);
        // depthwise conv reduce -> r0 (3136 x 768)
        dwconv_kernel<<<RROWS, 256, 0, stream>>>(y_bf, dw_w + (size_t)l * CDIM * 4,
                                                 dw_b + l * CDIM, r0_bf);
        // pw: r0 @ pw_w + b  (3136 x 960 x 768) -> fp32, NR=25 NC=8
        gemm_kernel<1><<<25 * 8, 256, 0, stream>>>(r0_bf, wl + offPW, pw_b + l * CNDIM,
                                                   pw_f, nullptr, RROWS, CNDIM, CDIM, 25, 8);
        // norm_act: LN(eps 1e-5) + GELU -> r
        ln_kernel<<<RROWS / 4, 256, 0, stream>>>(pw_f, lnr_g + l * CNDIM, lnr_b + l * CNDIM,
                                                 r_bf, RROWS, CNDIM, 1e-5f, 1);
        // fused kv = r @ [k_w | v_w]  (3136 x 1728 x 960), NR=25 NC=14
        gemm_kernel<0><<<25 * 14, 256, 0, stream>>>(r_bf, wl + offKV, nullptr, nullptr,
                                                    kv_bf, RROWS, KVN, CNDIM, 25, 14);
        // attention -> o (bf16)
        attn_kernel<<<BSZ * NHEAD, 256, 0, stream>>>(q_bf, kv_bf, o_bf);
        // x += o @ proj_w + proj_b  (12544 x 768 x 768), NR=98 NC=6
        gemm_kernel<2><<<98 * 6, 256, 0, stream>>>(o_bf, wl + offPJ, proj_b + l * CDIM,
                                                   xout, nullptr, ROWS, CDIM, CDIM, 98, 6);
        // LN2 -> z
        ln_kernel<<<ROWS / 4, 256, 0, stream>>>(xout, ln2_g + l * CDIM, ln2_b + l * CDIM,
                                                z_bf, ROWS, CDIM, 1e-6f, 0);
        // h = gelu(z @ fc1 + b)  (12544 x 3072 x 768), NR=98 NC=24
        gemm_kernel<3><<<98 * 24, 256, 0, stream>>>(z_bf, wl + offF1, fc1_b + l * HIDDIM,
                                                    nullptr, h_bf, ROWS, HIDDIM, CDIM, 98, 24);
        // x += h @ fc2 + b  (12544 x 768 x 3072), NR=98 NC=6
        gemm_kernel<2><<<98 * 6, 256, 0, stream>>>(h_bf, wl + offF2, fc2_b + l * CDIM,
                                                   xout, nullptr, ROWS, CDIM, HIDDIM, 98, 6);
    }
}